// Round 1
// baseline (291.665 us; speedup 1.0000x reference)
//
#include <hip/hip_runtime.h>
#include <hip/hip_bf16.h>

typedef unsigned short ushort_t;
typedef __attribute__((ext_vector_type(8))) short bf16x8;
typedef __attribute__((ext_vector_type(4))) float f32x4;
typedef __attribute__((ext_vector_type(4))) int i32x4;
typedef __attribute__((ext_vector_type(2))) int i32x2;

#define MFMA16(A, B, C) __builtin_amdgcn_mfma_f32_16x16x32_bf16(A, B, C, 0, 0, 0)

static constexpr int BATCH = 4;
static constexpr int DEP = 2048;     // sequence depth
static constexpr int NH = 8;         // heads
static constexpr int CW = 128;       // per-head q/k/v width (C*F = V*F = 128)
static constexpr int HBn = 32;       // NH*BATCH
static constexpr float INVTEMP = 0.022097086912079608f;  // 1/sqrt(2048)

static __device__ __forceinline__ ushort_t f2bf(float f) {
  __hip_bfloat16 h = __float2bfloat16(f);
  return __builtin_bit_cast(ushort_t, h);
}

// ---------------------------------------------------------------------------
// Kernel 1: pointwise QKV projection.
//   feat [8192 rows][64] f32;  W [64][1024] f32;  bias [1024]
//   q_ws/k_ws: bf16 [32 hb][2048 d][128 c]
//   vt_ws:     bf16 [32 hb][128 c][2048 d]   (pre-transposed for PV B-operand)
// grid: (256 row-tiles of 32, 12 = {q,k,v} x 4 col-quarters), 256 threads.
// ---------------------------------------------------------------------------
__global__ __launch_bounds__(256) void proj_kernel(
    const float* __restrict__ feat,
    const float* __restrict__ Wq, const float* __restrict__ bq,
    const float* __restrict__ Wk, const float* __restrict__ bk,
    const float* __restrict__ Wv, const float* __restrict__ bv,
    ushort_t* __restrict__ q_ws, ushort_t* __restrict__ k_ws,
    ushort_t* __restrict__ vt_ws) {
  const int rt = blockIdx.x;        // 32-row tile
  const int iw = blockIdx.y >> 2;   // 0=q 1=k 2=v
  const int ct = blockIdx.y & 3;    // 256-col quarter
  const float* W = (iw == 0) ? Wq : (iw == 1) ? Wk : Wv;
  const float* bs = (iw == 0) ? bq : (iw == 1) ? bk : bv;
  const int tid = threadIdx.x;

  __shared__ float fsm[32 * 64];        // feature tile (f32)
  __shared__ ushort_t re[32 * 256];     // bf16 repack for coalesced q/k writes

  {  // load feature tile: 32 rows x 64 f32 = 8KB contiguous
    const float4* fg = reinterpret_cast<const float4*>(feat + (size_t)rt * 32 * 64);
    float4* fs = reinterpret_cast<float4*>(fsm);
    fs[tid] = fg[tid];
    fs[tid + 256] = fg[tid + 256];
  }
  __syncthreads();

  const int j = ct * 256 + tid;  // output column within [0,1024)
  float acc[32];
  {
    const float b0 = bs[j];
#pragma unroll
    for (int r = 0; r < 32; ++r) acc[r] = b0;
  }
  for (int f4 = 0; f4 < 16; ++f4) {
    const float w0 = W[(f4 * 4 + 0) * 1024 + j];
    const float w1 = W[(f4 * 4 + 1) * 1024 + j];
    const float w2 = W[(f4 * 4 + 2) * 1024 + j];
    const float w3 = W[(f4 * 4 + 3) * 1024 + j];
#pragma unroll
    for (int r = 0; r < 32; ++r) {
      const float4 fv = *reinterpret_cast<const float4*>(&fsm[r * 64 + f4 * 4]);
      acc[r] = fmaf(fv.x, w0, acc[r]);
      acc[r] = fmaf(fv.y, w1, acc[r]);
      acc[r] = fmaf(fv.z, w2, acc[r]);
      acc[r] = fmaf(fv.w, w3, acc[r]);
    }
  }

  const int b = (rt * 32) >> 11;      // batch index (tiles never straddle)
  const int d0 = (rt * 32) & 2047;    // depth base
  if (iw == 2) {
    // v: write transposed [hb][c][d] — each thread owns 32 consecutive d.
    const int h = j >> 7, cc = j & 127;
    ushort_t us[32];
#pragma unroll
    for (int r = 0; r < 32; ++r) us[r] = f2bf(acc[r]);
    ushort_t* dst = vt_ws + ((size_t)((h * BATCH + b) * CW + cc)) * DEP + d0;
#pragma unroll
    for (int i = 0; i < 4; ++i) {
      unsigned int a0 = us[8 * i + 0] | ((unsigned int)us[8 * i + 1] << 16);
      unsigned int a1 = us[8 * i + 2] | ((unsigned int)us[8 * i + 3] << 16);
      unsigned int a2 = us[8 * i + 4] | ((unsigned int)us[8 * i + 5] << 16);
      unsigned int a3 = us[8 * i + 6] | ((unsigned int)us[8 * i + 7] << 16);
      i32x4 v4 = {(int)a0, (int)a1, (int)a2, (int)a3};
      *reinterpret_cast<i32x4*>(dst + i * 8) = v4;
    }
  } else {
    // q/k: repack through LDS, write [hb][d][c] with 16B stores.
    ushort_t* wsb = (iw == 0) ? q_ws : k_ws;
#pragma unroll
    for (int r = 0; r < 32; ++r) re[r * 256 + tid] = f2bf(acc[r]);
    __syncthreads();
#pragma unroll
    for (int i = 0; i < 4; ++i) {
      const int id = tid + i * 256;       // 1024 chunks of 8 bf16
      const int r = id >> 5;
      const int c8 = (id & 31) * 8;
      const int jj = ct * 256 + c8;
      const int hh = jj >> 7, c2 = jj & 127;
      ushort_t* dst = wsb + ((size_t)((hh * BATCH + b) * DEP) + d0 + r) * CW + c2;
      *reinterpret_cast<i32x4*>(dst) = *reinterpret_cast<const i32x4*>(&re[r * 256 + c8]);
    }
  }
}

// ---------------------------------------------------------------------------
// Kernel 2: fused attention. grid 512 = 32 hb x 16 q-tiles(128), 256 threads.
// Swapped QK^T: S^T frags (row=key, col=q). Pass 1: rowsums of exp(s/T).
// Pass 2: recompute, write attn (f32), P->LDS (bf16), PV accumulate.
// 4 waves split the q-tile (32 q each); each wave covers all 64 keys/iter.
// ---------------------------------------------------------------------------
__global__ __launch_bounds__(256, 2) void attn_kernel(
    const ushort_t* __restrict__ q_ws, const ushort_t* __restrict__ k_ws,
    const ushort_t* __restrict__ vt_ws, float* __restrict__ out,
    float* __restrict__ attn) {
  const int bid = blockIdx.x;
  const int hb = bid >> 4;
  const int qbase = (bid & 15) * 128;
  const int tid = threadIdx.x;
  const int w = tid >> 6;
  const int l = tid & 63;
  const int lg = l >> 4, ll = l & 15;
  const int swz = (ll & 7) << 4;

  __shared__ ushort_t k_lds[64 * 128];  // [key][feat], row 256B, XOR-swizzled
  __shared__ ushort_t v_lds[128 * 64];  // [c][key],   row 128B, XOR-swizzled
  __shared__ ushort_t p_lds[128 * 64];  // [q][key],   row 128B, XOR-swizzled

  // Q fragments hoisted to registers (B-operand: col=q, k=feat)
  bf16x8 qf[2][4];
  const int qw = qbase + 32 * w;
#pragma unroll
  for (int n = 0; n < 2; ++n)
#pragma unroll
    for (int ks = 0; ks < 4; ++ks)
      qf[n][ks] = *reinterpret_cast<const bf16x8*>(
          q_ws + ((size_t)(hb * DEP + qw + 16 * n + ll) * CW + ks * 32 + lg * 8));

  float rs[2] = {0.f, 0.f};

  // ---- pass 1: row sums ----
  for (int kt = 0; kt < 32; ++kt) {
    const int ktb = kt * 64;
#pragma unroll
    for (int i = 0; i < 4; ++i) {  // stage K tile: 64 keys x 128 feat
      const int id = tid + i * 256;
      const int key = id >> 4, f8 = id & 15;
      i32x4 val = *reinterpret_cast<const i32x4*>(
          k_ws + ((size_t)(hb * DEP + ktb + key) * CW + f8 * 8));
      const int boff = (key * 256 + f8 * 16) ^ ((key & 7) << 4);
      *reinterpret_cast<i32x4*>((char*)k_lds + boff) = val;
    }
    __syncthreads();
    f32x4 accS[4][2];
#pragma unroll
    for (int m = 0; m < 4; ++m)
#pragma unroll
      for (int n = 0; n < 2; ++n) accS[m][n] = (f32x4){0.f, 0.f, 0.f, 0.f};
#pragma unroll
    for (int ks = 0; ks < 4; ++ks) {
      bf16x8 ka[4];
#pragma unroll
      for (int m = 0; m < 4; ++m) {
        const int row = 16 * m + ll;
        const int boff = (row * 256 + ks * 64 + lg * 16) ^ swz;
        ka[m] = *reinterpret_cast<const bf16x8*>((const char*)k_lds + boff);
      }
#pragma unroll
      for (int m = 0; m < 4; ++m)
#pragma unroll
        for (int n = 0; n < 2; ++n) accS[m][n] = MFMA16(ka[m], qf[n][ks], accS[m][n]);
    }
#pragma unroll
    for (int m = 0; m < 4; ++m)
#pragma unroll
      for (int n = 0; n < 2; ++n)
#pragma unroll
        for (int r = 0; r < 4; ++r) rs[n] += __expf(accS[m][n][r] * INVTEMP);
    __syncthreads();
  }
#pragma unroll
  for (int n = 0; n < 2; ++n) {
    rs[n] += __shfl_xor(rs[n], 16);
    rs[n] += __shfl_xor(rs[n], 32);
  }
  const float inv[2] = {1.f / rs[0], 1.f / rs[1]};

  // ---- pass 2: attn write + PV ----
  f32x4 accO[8][2];
#pragma unroll
  for (int mc = 0; mc < 8; ++mc)
#pragma unroll
    for (int n = 0; n < 2; ++n) accO[mc][n] = (f32x4){0.f, 0.f, 0.f, 0.f};

  for (int kt = 0; kt < 32; ++kt) {
    const int ktb = kt * 64;
#pragma unroll
    for (int i = 0; i < 4; ++i) {  // stage K tile
      const int id = tid + i * 256;
      const int key = id >> 4, f8 = id & 15;
      i32x4 val = *reinterpret_cast<const i32x4*>(
          k_ws + ((size_t)(hb * DEP + ktb + key) * CW + f8 * 8));
      const int boff = (key * 256 + f8 * 16) ^ ((key & 7) << 4);
      *reinterpret_cast<i32x4*>((char*)k_lds + boff) = val;
    }
#pragma unroll
    for (int i = 0; i < 4; ++i) {  // stage V^T tile: 128 c x 64 keys
      const int id = tid + i * 256;
      const int c = id >> 3, k8 = id & 7;
      i32x4 val = *reinterpret_cast<const i32x4*>(
          vt_ws + ((size_t)(hb * CW + c) * DEP + ktb + k8 * 8));
      const int boff = (c * 128 + k8 * 16) ^ ((c & 7) << 4);
      *reinterpret_cast<i32x4*>((char*)v_lds + boff) = val;
    }
    __syncthreads();

    f32x4 accS[4][2];
#pragma unroll
    for (int m = 0; m < 4; ++m)
#pragma unroll
      for (int n = 0; n < 2; ++n) accS[m][n] = (f32x4){0.f, 0.f, 0.f, 0.f};
#pragma unroll
    for (int ks = 0; ks < 4; ++ks) {
      bf16x8 ka[4];
#pragma unroll
      for (int m = 0; m < 4; ++m) {
        const int row = 16 * m + ll;
        const int boff = (row * 256 + ks * 64 + lg * 16) ^ swz;
        ka[m] = *reinterpret_cast<const bf16x8*>((const char*)k_lds + boff);
      }
#pragma unroll
      for (int m = 0; m < 4; ++m)
#pragma unroll
        for (int n = 0; n < 2; ++n) accS[m][n] = MFMA16(ka[m], qf[n][ks], accS[m][n]);
    }

    // normalize, emit attn (f32) + P (bf16 -> LDS)
#pragma unroll
    for (int m = 0; m < 4; ++m)
#pragma unroll
      for (int n = 0; n < 2; ++n) {
        f32x4 p;
#pragma unroll
        for (int r = 0; r < 4; ++r) p[r] = __expf(accS[m][n][r] * INVTEMP) * inv[n];
        const int q = qw + 16 * n + ll;
        const int key = ktb + 16 * m + 4 * lg;
        *reinterpret_cast<f32x4*>(attn + (size_t)hb * DEP * DEP + (size_t)q * DEP + key) = p;
        unsigned int lo = f2bf(p[0]) | ((unsigned int)f2bf(p[1]) << 16);
        unsigned int hi = f2bf(p[2]) | ((unsigned int)f2bf(p[3]) << 16);
        i32x2 pw = {(int)lo, (int)hi};
        const int boff = ((32 * w + 16 * n + ll) * 128 + (16 * m + 4 * lg) * 2) ^ swz;
        *reinterpret_cast<i32x2*>((char*)p_lds + boff) = pw;
      }

    // PV: out^T[c][q] += V^T[c][key] * P[q][key]  (same-wave LDS, DS in-order)
#pragma unroll
    for (int kk = 0; kk < 2; ++kk) {
      bf16x8 pb[2];
#pragma unroll
      for (int n = 0; n < 2; ++n) {
        const int boff = ((32 * w + 16 * n + ll) * 128 + (kk * 32 + lg * 8) * 2) ^ swz;
        pb[n] = *reinterpret_cast<const bf16x8*>((const char*)p_lds + boff);
      }
#pragma unroll
      for (int mc = 0; mc < 8; ++mc) {
        const int boff = ((16 * mc + ll) * 128 + (kk * 32 + lg * 8) * 2) ^ swz;
        bf16x8 va = *reinterpret_cast<const bf16x8*>((const char*)v_lds + boff);
#pragma unroll
        for (int n = 0; n < 2; ++n) accO[mc][n] = MFMA16(va, pb[n], accO[mc][n]);
      }
    }
    __syncthreads();
  }

  // epilogue: out^T frags -> final [b][h*2+vc][d][f] layout (4 consecutive c = float4)
  const int hh = hb >> 2, b = hb & 3;
#pragma unroll
  for (int mc = 0; mc < 8; ++mc)
#pragma unroll
    for (int n = 0; n < 2; ++n) {
      const int c0 = 16 * mc + 4 * lg;
      const int qg = qbase + 32 * w + 16 * n + ll;
      float* dst = out + (((size_t)(b * 16 + hh * 2 + (c0 >> 6)) * DEP + qg) * 64 + (c0 & 63));
      *reinterpret_cast<f32x4*>(dst) = accO[mc][n];
    }
}

extern "C" void kernel_launch(void* const* d_in, const int* in_sizes, int n_in,
                              void* d_out, int out_size, void* d_ws, size_t ws_size,
                              hipStream_t stream) {
  const float* feat = (const float*)d_in[0];
  const float* Wq = (const float*)d_in[1];
  const float* bq = (const float*)d_in[2];
  const float* Wk = (const float*)d_in[3];
  const float* bk = (const float*)d_in[4];
  const float* Wv = (const float*)d_in[5];
  const float* bv = (const float*)d_in[6];

  ushort_t* q_ws = (ushort_t*)d_ws;
  ushort_t* k_ws = q_ws + (size_t)HBn * DEP * CW;
  ushort_t* vt_ws = k_ws + (size_t)HBn * DEP * CW;

  float* out = (float*)d_out;
  float* attn = out + (size_t)BATCH * 16 * DEP * 64;  // 8388608 floats

  hipLaunchKernelGGL(proj_kernel, dim3(256, 12), dim3(256), 0, stream,
                     feat, Wq, bq, Wk, bk, Wv, bv, q_ws, k_ws, vt_ws);
  hipLaunchKernelGGL(attn_kernel, dim3(512), dim3(256), 0, stream,
                     q_ws, k_ws, vt_ws, out, attn);
}